// Round 1
// baseline (321.074 us; speedup 1.0000x reference)
//
#include <hip/hip_runtime.h>
#include <hip/hip_bf16.h>

#define B_ 16
#define N_ 2048
#define D_ 128

typedef __bf16 bf16_t;
typedef bf16_t bf16x8 __attribute__((ext_vector_type(8)));
typedef float f32x4 __attribute__((ext_vector_type(4)));

// ---------------- K0: pack adj (fp32 0/1 matrix) into bitmask ----------------
// bits[i][w] (w<64, uint32) holds adj[i][w*32 .. w*32+31]
__global__ __launch_bounds__(256) void k_pack_adj(const float* __restrict__ adj,
                                                  unsigned int* __restrict__ bits) {
    int t = blockIdx.x * 256 + threadIdx.x;       // over N*N
    float v = adj[t];
    unsigned long long m = __ballot(v > 0.5f);    // 64 bits, lane l <-> j0+l
    if ((t & 63) == 0) {
        int i = t >> 11;          // row
        int j = t & 2047;         // col (multiple of 64 here)
        bits[i * 64 + (j >> 5)]     = (unsigned int)m;
        bits[i * 64 + (j >> 5) + 1] = (unsigned int)(m >> 32);
    }
}

// ---------------- K1: emb GEMM: seq_ftsT[b][d][n] = sum_i x[b][n][i]*W[d][i] + be[d]
// block: 64 nodes x 64 outputs, K=128 in two stages of 64. 256 threads.
__global__ __launch_bounds__(256) void k_emb(const float* __restrict__ x,
                                             const float* __restrict__ W,
                                             const float* __restrict__ be,
                                             float* __restrict__ sfT) {
    __shared__ float xs[64 * 68];   // [k][n] padded
    __shared__ float ws2[64 * 68];  // [k][d] padded
    int blk = blockIdx.x;           // 1024 blocks
    int b   = blk >> 6;
    int rem = blk & 63;
    int n0  = (rem >> 1) * 64;
    int d0  = (rem & 1) * 64;
    int tid = threadIdx.x;
    int tx = tid & 15, ty = tid >> 4;    // tx: n-dir, ty: d-dir
    const float* xrow = x + ((size_t)b * N_ + n0) * D_;
    const float* wrow = W + (size_t)d0 * D_;

    f32x4 acc[4];                        // acc[j(d)] = float4 over i(n)
#pragma unroll
    for (int j = 0; j < 4; ++j) acc[j] = (f32x4){0.f, 0.f, 0.f, 0.f};

    for (int s = 0; s < 2; ++s) {
        __syncthreads();
        int r   = tid >> 4;              // 0..15
        int c0l = (tid & 15) * 4;        // 0..60
#pragma unroll
        for (int p = 0; p < 4; ++p) {
            int row = p * 16 + r;
            f32x4 xv = *(const f32x4*)(xrow + (size_t)row * D_ + s * 64 + c0l);
            f32x4 wv = *(const f32x4*)(wrow + (size_t)row * D_ + s * 64 + c0l);
#pragma unroll
            for (int c = 0; c < 4; ++c) {
                xs[(c0l + c) * 68 + row]  = xv[c];
                ws2[(c0l + c) * 68 + row] = wv[c];
            }
        }
        __syncthreads();
        for (int kk = 0; kk < 64; ++kk) {
            f32x4 xv = *(const f32x4*)&xs[kk * 68 + tx * 4];
            f32x4 wv = *(const f32x4*)&ws2[kk * 68 + ty * 4];
#pragma unroll
            for (int j = 0; j < 4; ++j)
#pragma unroll
                for (int i = 0; i < 4; ++i)
                    acc[j][i] += wv[j] * xv[i];
        }
    }
    f32x4 bv = *(const f32x4*)(be + d0 + ty * 4);
#pragma unroll
    for (int j = 0; j < 4; ++j) {
        int d = d0 + ty * 4 + j;
        f32x4 o = acc[j];
        o[0] += bv[j]; o[1] += bv[j]; o[2] += bv[j]; o[3] += bv[j];
        *(f32x4*)(sfT + ((size_t)b * D_ + d) * N_ + n0 + tx * 4) = o;
    }
}

// ---------------- K2: q,k projections + precomputed exps per (b,node) --------
__global__ __launch_bounds__(64) void k_qk(const float* __restrict__ sfT,
                                           const float* __restrict__ wq,
                                           const float* __restrict__ bq,
                                           const float* __restrict__ wk,
                                           const float* __restrict__ bk,
                                           float* __restrict__ qa, float* __restrict__ ka,
                                           float* __restrict__ Eq, float* __restrict__ eqs,
                                           float* __restrict__ Ek, float* __restrict__ eks) {
    int blk = blockIdx.x;                 // 512 blocks
    int b = blk >> 5;
    int n = (blk & 31) * 64 + threadIdx.x;
    const float* base = sfT + (size_t)b * D_ * N_ + n;
    float aq = 0.f, ak = 0.f;
    for (int d = 0; d < D_; ++d) {
        float v = base[(size_t)d * N_];   // coalesced over lanes
        aq += v * wq[d];
        ak += v * wk[d];
    }
    aq += bq[0]; ak += bk[0];
    int idx = b * N_ + n;
    qa[idx] = aq;            ka[idx] = ak;
    Eq[idx] = expf(aq);      eqs[idx] = expf(0.01f * aq);
    Ek[idx] = expf(ak);      eks[idx] = expf(0.01f * ak);
}

// ---------------- K3: denom[b][j] = sum_i V(b,i,j) ---------------------------
__global__ __launch_bounds__(256) void k_denom(const unsigned int* __restrict__ bits,
                                               const float* __restrict__ qa,
                                               const float* __restrict__ ka,
                                               const float* __restrict__ Eq,
                                               const float* __restrict__ eqs,
                                               const float* __restrict__ Ek,
                                               const float* __restrict__ eks,
                                               float* __restrict__ denom) {
    int jt  = blockIdx.x;     // 0..7
    int b   = blockIdx.y;     // 0..15
    int seg = blockIdx.z;     // 0..3
    int j = jt * 256 + threadIdx.x;
    float qj  = qa[b * N_ + j];
    float Eqj = Eq[b * N_ + j];
    float eqj = eqs[b * N_ + j];
    int shift = j & 31;
    int wid   = j >> 5;
    float acc = 0.f;
    int i0 = seg * 512;
    for (int i = i0; i < i0 + 512; ++i) {
        float kk  = ka[b * N_ + i];      // uniform -> s_load
        float Ekk = Ek[b * N_ + i];
        float ekk = eks[b * N_ + i];
        unsigned int w = bits[i * 64 + wid];
        float z  = kk + qj;
        float f1 = z > 0.f ? Ekk : ekk;
        float f2 = z > 0.f ? Eqj : eqj;
        float v  = f1 * f2;
        acc += ((w >> shift) & 1u) ? v : 1.0f;
    }
    atomicAdd(&denom[b * N_ + j], acc);
}

// ---------------- K3b: Pt[b][d][j] = bf16(seq_ftsT / denom[b][j]) ------------
__global__ __launch_bounds__(256) void k_scale(const float* __restrict__ sfT,
                                               const float* __restrict__ denom,
                                               bf16_t* __restrict__ Pt) {
    size_t t = (size_t)blockIdx.x * 256 + threadIdx.x;   // over B*D*N
    int j  = (int)(t & (N_ - 1));
    int bd = (int)(t >> 11);
    int b  = bd >> 7;
    float v = sfT[t] / denom[b * N_ + j];
    Pt[t] = (bf16_t)v;
}

// ---------------- K4: vals = A @ P via MFMA, A generated in-register ----------
// block: 64 rows(i) x 128 cols(d), 4 waves (16 rows each), K-loop over j in 32s
__global__ __launch_bounds__(256) void k_attn(const float* __restrict__ qa,
                                              const float* __restrict__ ka,
                                              const float* __restrict__ Eq,
                                              const float* __restrict__ eqs,
                                              const float* __restrict__ Ek,
                                              const float* __restrict__ eks,
                                              const unsigned char* __restrict__ adjbytes,
                                              const bf16_t* __restrict__ Pt,
                                              float* __restrict__ out) {
    int b     = blockIdx.y;
    int ibase = blockIdx.x * 64;
    int tid   = threadIdx.x;
    int wave  = tid >> 6;
    int lane  = tid & 63;
    int m16   = lane & 15;
    int quad  = lane >> 4;
    int i = ibase + wave * 16 + m16;        // this lane's A-row
    float kR  = ka[b * N_ + i];
    float EkR = Ek[b * N_ + i];
    float ekR = eks[b * N_ + i];
    const float*  qp  = qa  + b * N_;
    const float*  Eqp = Eq  + b * N_;
    const float*  eqp = eqs + b * N_;
    const bf16_t* PtB = Pt + (size_t)b * D_ * N_;

    f32x4 acc[8];
#pragma unroll
    for (int t = 0; t < 8; ++t) acc[t] = (f32x4){0.f, 0.f, 0.f, 0.f};

    for (int jb = 0; jb < N_; jb += 32) {
        int j0 = jb + quad * 8;
        f32x4 q0 = *(const f32x4*)(qp  + j0);
        f32x4 q1 = *(const f32x4*)(qp  + j0 + 4);
        f32x4 E0 = *(const f32x4*)(Eqp + j0);
        f32x4 E1 = *(const f32x4*)(Eqp + j0 + 4);
        f32x4 e0 = *(const f32x4*)(eqp + j0);
        f32x4 e1 = *(const f32x4*)(eqp + j0 + 4);
        unsigned int byte = adjbytes[i * 256 + (j0 >> 3)];
        bf16x8 af;
#pragma unroll
        for (int t = 0; t < 8; ++t) {
            float qv = (t < 4) ? q0[t] : q1[t - 4];
            float Ev = (t < 4) ? E0[t] : E1[t - 4];
            float ev = (t < 4) ? e0[t] : e1[t - 4];
            float z  = kR + qv;
            float f1 = (z > 0.f) ? EkR : ekR;
            float f2 = (z > 0.f) ? Ev : ev;
            float v  = f1 * f2;
            v = ((byte >> t) & 1u) ? v : 1.0f;
            af[t] = (bf16_t)v;
        }
#pragma unroll
        for (int nt = 0; nt < 8; ++nt) {
            bf16x8 bv = *(const bf16x8*)(PtB + (size_t)(nt * 16 + m16) * N_ + j0);
            acc[nt] = __builtin_amdgcn_mfma_f32_16x16x32_bf16(af, bv, acc[nt], 0, 0, 0);
        }
    }
    int iout = ibase + wave * 16 + quad * 4;
#pragma unroll
    for (int nt = 0; nt < 8; ++nt) {
        int d = nt * 16 + m16;
#pragma unroll
        for (int r = 0; r < 4; ++r) {
            out[((size_t)b * N_ + (iout + r)) * D_ + d] = acc[nt][r];
        }
    }
}

extern "C" void kernel_launch(void* const* d_in, const int* in_sizes, int n_in,
                              void* d_out, int out_size, void* d_ws, size_t ws_size,
                              hipStream_t stream) {
    const float* x   = (const float*)d_in[0];
    const float* adj = (const float*)d_in[1];
    const float* W   = (const float*)d_in[2];
    const float* be  = (const float*)d_in[3];
    const float* wq  = (const float*)d_in[4];
    const float* bq  = (const float*)d_in[5];
    const float* wk  = (const float*)d_in[6];
    const float* bk  = (const float*)d_in[7];
    float* out = (float*)d_out;

    char* ws = (char*)d_ws;
    size_t off = 0;
    float* sfT = (float*)(ws + off);  off += (size_t)B_ * D_ * N_ * 4;   // 16 MB
    bf16_t* Pt = (bf16_t*)(ws + off); off += (size_t)B_ * D_ * N_ * 2;   // 8 MB
    float* qa  = (float*)(ws + off);  off += (size_t)B_ * N_ * 4;
    float* ka  = (float*)(ws + off);  off += (size_t)B_ * N_ * 4;
    float* Eq  = (float*)(ws + off);  off += (size_t)B_ * N_ * 4;
    float* eqs = (float*)(ws + off);  off += (size_t)B_ * N_ * 4;
    float* Ek  = (float*)(ws + off);  off += (size_t)B_ * N_ * 4;
    float* eks = (float*)(ws + off);  off += (size_t)B_ * N_ * 4;
    float* denom = (float*)(ws + off); off += (size_t)B_ * N_ * 4;
    unsigned int* bits = (unsigned int*)(ws + off); off += (size_t)N_ * 64 * 4; // 512 KB

    hipMemsetAsync(denom, 0, (size_t)B_ * N_ * 4, stream);

    k_pack_adj<<<N_ * N_ / 256, 256, 0, stream>>>(adj, bits);
    k_emb<<<1024, 256, 0, stream>>>(x, W, be, sfT);
    k_qk<<<512, 64, 0, stream>>>(sfT, wq, bq, wk, bk, qa, ka, Eq, eqs, Ek, eks);
    k_denom<<<dim3(8, 16, 4), 256, 0, stream>>>(bits, qa, ka, Eq, eqs, Ek, eks, denom);
    k_scale<<<B_ * D_ * N_ / 256, 256, 0, stream>>>(sfT, denom, Pt);
    k_attn<<<dim3(32, 16), 256, 0, stream>>>(qa, ka, Eq, eqs, Ek, eks,
                                             (const unsigned char*)bits, Pt, out);
}

// Round 2
// 307.230 us; speedup vs baseline: 1.0451x; 1.0451x over previous
//
#include <hip/hip_runtime.h>
#include <hip/hip_bf16.h>

#define B_ 16
#define N_ 2048
#define D_ 128

typedef __bf16 bf16_t;
typedef bf16_t bf16x8 __attribute__((ext_vector_type(8)));
typedef float f32x4 __attribute__((ext_vector_type(4)));

// ---------------- K0: pack adj (fp32 0/1 matrix) into bitmask ----------------
__global__ __launch_bounds__(256) void k_pack_adj(const float* __restrict__ adj,
                                                  unsigned int* __restrict__ bits) {
    int t = blockIdx.x * 256 + threadIdx.x;       // over N*N
    float v = adj[t];
    unsigned long long m = __ballot(v > 0.5f);
    if ((t & 63) == 0) {
        int i = t >> 11;
        int j = t & 2047;
        bits[i * 64 + (j >> 5)]     = (unsigned int)m;
        bits[i * 64 + (j >> 5) + 1] = (unsigned int)(m >> 32);
    }
}

// ---------------- K1: emb GEMM + fused q/k partial dot products --------------
// seq_ftsT[b][d][n] = sum_i x[b][n][i]*W[d][i] + be[d]
// qa[b][n] += sum_{d in tile} sfT * wq[d]   (atomics; bias added in k_exp)
__global__ __launch_bounds__(256) void k_emb(const float* __restrict__ x,
                                             const float* __restrict__ W,
                                             const float* __restrict__ be,
                                             const float* __restrict__ wq,
                                             const float* __restrict__ wk,
                                             float* __restrict__ sfT,
                                             float* __restrict__ qa,
                                             float* __restrict__ ka) {
    __shared__ float xs[64 * 68];   // [k][n] padded
    __shared__ float ws2[64 * 68];  // [k][d] padded
    __shared__ float qs[64], ks[64];
    int blk = blockIdx.x;           // 1024 blocks
    int b   = blk >> 6;
    int rem = blk & 63;
    int n0  = (rem >> 1) * 64;
    int d0  = (rem & 1) * 64;
    int tid = threadIdx.x;
    int tx = tid & 15, ty = tid >> 4;    // tx: n-dir, ty: d-dir
    const float* xrow = x + ((size_t)b * N_ + n0) * D_;
    const float* wrow = W + (size_t)d0 * D_;

    if (tid < 64) { qs[tid] = 0.f; ks[tid] = 0.f; }

    f32x4 acc[4];
#pragma unroll
    for (int j = 0; j < 4; ++j) acc[j] = (f32x4){0.f, 0.f, 0.f, 0.f};

    for (int s = 0; s < 2; ++s) {
        __syncthreads();
        int r   = tid >> 4;
        int c0l = (tid & 15) * 4;
#pragma unroll
        for (int p = 0; p < 4; ++p) {
            int row = p * 16 + r;
            f32x4 xv = *(const f32x4*)(xrow + (size_t)row * D_ + s * 64 + c0l);
            f32x4 wv = *(const f32x4*)(wrow + (size_t)row * D_ + s * 64 + c0l);
#pragma unroll
            for (int c = 0; c < 4; ++c) {
                xs[(c0l + c) * 68 + row]  = xv[c];
                ws2[(c0l + c) * 68 + row] = wv[c];
            }
        }
        __syncthreads();
        for (int kk = 0; kk < 64; ++kk) {
            f32x4 xv = *(const f32x4*)&xs[kk * 68 + tx * 4];
            f32x4 wv = *(const f32x4*)&ws2[kk * 68 + ty * 4];
#pragma unroll
            for (int j = 0; j < 4; ++j)
#pragma unroll
                for (int i = 0; i < 4; ++i)
                    acc[j][i] += wv[j] * xv[i];
        }
    }
    f32x4 bv  = *(const f32x4*)(be + d0 + ty * 4);
    f32x4 wqv = *(const f32x4*)(wq + d0 + ty * 4);
    f32x4 wkv = *(const f32x4*)(wk + d0 + ty * 4);
    float qp[4] = {0.f, 0.f, 0.f, 0.f};
    float kp[4] = {0.f, 0.f, 0.f, 0.f};
#pragma unroll
    for (int j = 0; j < 4; ++j) {
        int d = d0 + ty * 4 + j;
        f32x4 o = acc[j];
        o[0] += bv[j]; o[1] += bv[j]; o[2] += bv[j]; o[3] += bv[j];
#pragma unroll
        for (int i = 0; i < 4; ++i) {
            qp[i] += o[i] * wqv[j];
            kp[i] += o[i] * wkv[j];
        }
        *(f32x4*)(sfT + ((size_t)b * D_ + d) * N_ + n0 + tx * 4) = o;
    }
#pragma unroll
    for (int i = 0; i < 4; ++i) {
        atomicAdd(&qs[tx * 4 + i], qp[i]);
        atomicAdd(&ks[tx * 4 + i], kp[i]);
    }
    __syncthreads();
    if (tid < 64) {
        atomicAdd(&qa[b * N_ + n0 + tid], qs[tid]);
        atomicAdd(&ka[b * N_ + n0 + tid], ks[tid]);
    }
}

// ---------------- K2: add biases, compute exp tables -------------------------
__global__ __launch_bounds__(256) void k_exp(const float* __restrict__ bq,
                                             const float* __restrict__ bk,
                                             float* __restrict__ qa, float* __restrict__ ka,
                                             float* __restrict__ Eq, float* __restrict__ eqs,
                                             float* __restrict__ Ek, float* __restrict__ eks) {
    int t = blockIdx.x * 256 + threadIdx.x;   // over B*N
    float aq = qa[t] + bq[0];
    float ak = ka[t] + bk[0];
    qa[t] = aq;            ka[t] = ak;
    Eq[t] = expf(aq);      eqs[t] = expf(0.01f * aq);
    Ek[t] = expf(ak);      eks[t] = expf(0.01f * ak);
}

// ---------------- K3: denom[b][j] = sum_i V(b,i,j) ---------------------------
__global__ __launch_bounds__(256) void k_denom(const unsigned int* __restrict__ bits,
                                               const float* __restrict__ qa,
                                               const float* __restrict__ ka,
                                               const float* __restrict__ Eq,
                                               const float* __restrict__ eqs,
                                               const float* __restrict__ Ek,
                                               const float* __restrict__ eks,
                                               float* __restrict__ denom) {
    int jt  = blockIdx.x;     // 0..7
    int b   = blockIdx.y;     // 0..15
    int seg = blockIdx.z;     // 0..7
    int j = jt * 256 + threadIdx.x;
    float qj  = qa[b * N_ + j];
    float Eqj = Eq[b * N_ + j];
    float eqj = eqs[b * N_ + j];
    int shift = j & 31;
    int wid   = j >> 5;
    float acc = 0.f;
    int i0 = seg * 256;
#pragma unroll 8
    for (int i = i0; i < i0 + 256; ++i) {
        float kk  = ka[b * N_ + i];
        float Ekk = Ek[b * N_ + i];
        float ekk = eks[b * N_ + i];
        unsigned int w = bits[i * 64 + wid];
        float z  = kk + qj;
        float f1 = z > 0.f ? Ekk : ekk;
        float f2 = z > 0.f ? Eqj : eqj;
        float v  = f1 * f2;
        acc += ((w >> shift) & 1u) ? v : 1.0f;
    }
    atomicAdd(&denom[b * N_ + j], acc);
}

// ---------------- K3b: Pt[b][d][j] = bf16(seq_ftsT / denom[b][j]) ------------
__global__ __launch_bounds__(256) void k_scale(const float* __restrict__ sfT,
                                               const float* __restrict__ denom,
                                               bf16_t* __restrict__ Pt) {
    size_t t = (size_t)blockIdx.x * 256 + threadIdx.x;
    int j  = (int)(t & (N_ - 1));
    int bd = (int)(t >> 11);
    int b  = bd >> 7;
    float v = sfT[t] / denom[b * N_ + j];
    Pt[t] = (bf16_t)v;
}

// ---------------- K4: vals = A @ P via MFMA, register double-buffered --------
__global__ __launch_bounds__(256, 2) void k_attn(const float* __restrict__ qa,
                                                 const float* __restrict__ ka,
                                                 const float* __restrict__ Eq,
                                                 const float* __restrict__ eqs,
                                                 const float* __restrict__ Ek,
                                                 const float* __restrict__ eks,
                                                 const unsigned int* __restrict__ bits,
                                                 const bf16_t* __restrict__ Pt,
                                                 float* __restrict__ out) {
    int b     = blockIdx.y;
    int ibase = blockIdx.x * 64;
    int tid   = threadIdx.x;
    int wave  = tid >> 6;
    int lane  = tid & 63;
    int m16   = lane & 15;
    int quad  = lane >> 4;
    int i = ibase + wave * 16 + m16;        // this lane's A-row
    float kR  = ka[b * N_ + i];
    float EkR = Ek[b * N_ + i];
    float ekR = eks[b * N_ + i];
    const float* qp  = qa  + b * N_;
    const float* Eqp = Eq  + b * N_;
    const float* eqp = eqs + b * N_;
    const unsigned int* brow = bits + i * 64;
    const bf16_t* ptRow = Pt + (size_t)b * D_ * N_ + (size_t)m16 * N_;

    f32x4 acc[8];
#pragma unroll
    for (int t = 0; t < 8; ++t) acc[t] = (f32x4){0.f, 0.f, 0.f, 0.f};

    // double-buffered prefetch state
    f32x4 q0[2], q1[2], E0[2], E1[2], e0[2], e1[2];
    unsigned int wb[2];
    bf16x8 bv[2][8];

    auto issue = [&](int buf, int jb) {
        int j0 = jb + quad * 8;
        q0[buf] = *(const f32x4*)(qp  + j0);
        q1[buf] = *(const f32x4*)(qp  + j0 + 4);
        E0[buf] = *(const f32x4*)(Eqp + j0);
        E1[buf] = *(const f32x4*)(Eqp + j0 + 4);
        e0[buf] = *(const f32x4*)(eqp + j0);
        e1[buf] = *(const f32x4*)(eqp + j0 + 4);
        wb[buf] = brow[jb >> 5];
#pragma unroll
        for (int nt = 0; nt < 8; ++nt)
            bv[buf][nt] = *(const bf16x8*)(ptRow + (size_t)nt * 16 * N_ + j0);
    };

    issue(0, 0);

    for (int jb = 0; jb < N_; jb += 64) {
#pragma unroll
        for (int u = 0; u < 2; ++u) {
            int jcur = jb + u * 32;
            issue(u ^ 1, (jcur + 32) & (N_ - 1));   // prefetch next (wraps on last)
            bf16x8 af;
#pragma unroll
            for (int t = 0; t < 8; ++t) {
                float qv = (t < 4) ? q0[u][t] : q1[u][t - 4];
                float Ev = (t < 4) ? E0[u][t] : E1[u][t - 4];
                float ev = (t < 4) ? e0[u][t] : e1[u][t - 4];
                float z  = kR + qv;
                float f1 = (z > 0.f) ? EkR : ekR;
                float f2 = (z > 0.f) ? Ev : ev;
                float v  = f1 * f2;
                v = ((wb[u] >> (quad * 8 + t)) & 1u) ? v : 1.0f;
                af[t] = (bf16_t)v;
            }
#pragma unroll
            for (int nt = 0; nt < 8; ++nt)
                acc[nt] = __builtin_amdgcn_mfma_f32_16x16x32_bf16(af, bv[u][nt], acc[nt], 0, 0, 0);
        }
    }
    int iout = ibase + wave * 16 + quad * 4;
#pragma unroll
    for (int nt = 0; nt < 8; ++nt) {
        int d = nt * 16 + m16;
#pragma unroll
        for (int r = 0; r < 4; ++r) {
            out[((size_t)b * N_ + (iout + r)) * D_ + d] = acc[nt][r];
        }
    }
}

extern "C" void kernel_launch(void* const* d_in, const int* in_sizes, int n_in,
                              void* d_out, int out_size, void* d_ws, size_t ws_size,
                              hipStream_t stream) {
    const float* x   = (const float*)d_in[0];
    const float* adj = (const float*)d_in[1];
    const float* W   = (const float*)d_in[2];
    const float* be  = (const float*)d_in[3];
    const float* wq  = (const float*)d_in[4];
    const float* bq  = (const float*)d_in[5];
    const float* wk  = (const float*)d_in[6];
    const float* bk  = (const float*)d_in[7];
    float* out = (float*)d_out;

    char* ws = (char*)d_ws;
    size_t off = 0;
    float* sfT = (float*)(ws + off);  off += (size_t)B_ * D_ * N_ * 4;   // 16 MB
    bf16_t* Pt = (bf16_t*)(ws + off); off += (size_t)B_ * D_ * N_ * 2;   // 8 MB
    float* qa  = (float*)(ws + off);  off += (size_t)B_ * N_ * 4;
    float* ka  = (float*)(ws + off);  off += (size_t)B_ * N_ * 4;
    float* denom = (float*)(ws + off); off += (size_t)B_ * N_ * 4;
    float* Eq  = (float*)(ws + off);  off += (size_t)B_ * N_ * 4;
    float* eqs = (float*)(ws + off);  off += (size_t)B_ * N_ * 4;
    float* Ek  = (float*)(ws + off);  off += (size_t)B_ * N_ * 4;
    float* eks = (float*)(ws + off);  off += (size_t)B_ * N_ * 4;
    unsigned int* bits = (unsigned int*)(ws + off); off += (size_t)N_ * 64 * 4; // 512 KB

    // zero qa, ka, denom (contiguous)
    hipMemsetAsync(qa, 0, (size_t)3 * B_ * N_ * 4, stream);

    k_pack_adj<<<N_ * N_ / 256, 256, 0, stream>>>(adj, bits);
    k_emb<<<1024, 256, 0, stream>>>(x, W, be, wq, wk, sfT, qa, ka);
    k_exp<<<B_ * N_ / 256, 256, 0, stream>>>(bq, bk, qa, ka, Eq, eqs, Ek, eks);
    k_denom<<<dim3(8, 16, 8), 256, 0, stream>>>(bits, qa, ka, Eq, eqs, Ek, eks, denom);
    k_scale<<<B_ * D_ * N_ / 256, 256, 0, stream>>>(sfT, denom, Pt);
    k_attn<<<dim3(32, 16), 256, 0, stream>>>(qa, ka, Eq, eqs, Ek, eks, bits, Pt, out);
}

// Round 3
// 224.074 us; speedup vs baseline: 1.4329x; 1.3711x over previous
//
#include <hip/hip_runtime.h>
#include <hip/hip_bf16.h>
#include <stdint.h>

#define B_ 16
#define N_ 2048
#define D_ 128

typedef __bf16 bf16_t;
typedef bf16_t bf16x8 __attribute__((ext_vector_type(8)));
typedef float f32x4 __attribute__((ext_vector_type(4)));

// ---------------- K0: pack adj (fp32 0/1 matrix) into bitmask ----------------
__global__ __launch_bounds__(256) void k_pack_adj(const float* __restrict__ adj,
                                                  unsigned int* __restrict__ bits) {
    int t = blockIdx.x * 256 + threadIdx.x;       // over N*N
    float v = adj[t];
    unsigned long long m = __ballot(v > 0.5f);
    if ((t & 63) == 0) {
        int i = t >> 11;
        int j = t & 2047;
        bits[i * 64 + (j >> 5)]     = (unsigned int)m;
        bits[i * 64 + (j >> 5) + 1] = (unsigned int)(m >> 32);
    }
}

// ---------------- K1: emb GEMM (128n x 128d tile, 8x8 regs) + fused q/k ------
// seq_ftsT[b][d][n] = sum_k x[b][n][k]*W[d][k] + be[d]
// qa[b][n] = sum_d sfT*wq[d] (bias added in k_exp); same for ka.
__global__ __launch_bounds__(256, 1) void k_emb(const float* __restrict__ x,
                                                const float* __restrict__ W,
                                                const float* __restrict__ be,
                                                const float* __restrict__ wq,
                                                const float* __restrict__ wk,
                                                float* __restrict__ sfT,
                                                float* __restrict__ qa,
                                                float* __restrict__ ka) {
    __shared__ float xs[32][132];
    __shared__ float ws[32][132];
    __shared__ float qs[128], ks[128];
    int b  = blockIdx.y;
    int n0 = blockIdx.x * 128;
    int tid = threadIdx.x;
    int tx = tid & 15, ty = tid >> 4;   // tx: n-dir, ty: d-dir
    if (tid < 128) { qs[tid] = 0.f; ks[tid] = 0.f; }

    float acc[8][8] = {};
    f32x4 xr[4], wr[4];

    auto loadregs = [&](int kc) {
#pragma unroll
        for (int s = 0; s < 4; ++s) {
            int p = tid + 256 * s;        // 0..1023
            int n = p >> 3, kq = p & 7;
            xr[s] = *(const f32x4*)(x + ((size_t)(b * N_ + n0 + n)) * D_ + kc * 32 + kq * 4);
            wr[s] = *(const f32x4*)(W + (size_t)n * D_ + kc * 32 + kq * 4);  // n doubles as d-index
        }
    };
    auto writelds = [&]() {
#pragma unroll
        for (int s = 0; s < 4; ++s) {
            int p = tid + 256 * s;
            int n = p >> 3, kq = p & 7;
#pragma unroll
            for (int u = 0; u < 4; ++u) {
                xs[kq * 4 + u][n] = xr[s][u];
                ws[kq * 4 + u][n] = wr[s][u];
            }
        }
    };

    loadregs(0);
    for (int kc = 0; kc < 4; ++kc) {
        writelds();
        __syncthreads();
        if (kc < 3) loadregs(kc + 1);     // global prefetch overlaps compute
        for (int k = 0; k < 32; ++k) {
            f32x4 xv0 = *(const f32x4*)&xs[k][tx * 8];
            f32x4 xv1 = *(const f32x4*)&xs[k][tx * 8 + 4];
            f32x4 wv0 = *(const f32x4*)&ws[k][ty * 8];
            f32x4 wv1 = *(const f32x4*)&ws[k][ty * 8 + 4];
#pragma unroll
            for (int i = 0; i < 8; ++i) {
                float xi = (i < 4) ? xv0[i] : xv1[i - 4];
#pragma unroll
                for (int j = 0; j < 8; ++j) {
                    float wj = (j < 4) ? wv0[j] : wv1[j - 4];
                    acc[i][j] += xi * wj;
                }
            }
        }
        __syncthreads();
    }

    float qp[8] = {}, kp[8] = {};
#pragma unroll
    for (int j = 0; j < 8; ++j) {
        int d = ty * 8 + j;
        float bj  = be[d];
        float wqj = wq[d];
        float wkj = wk[d];
        f32x4 o0, o1;
#pragma unroll
        for (int i = 0; i < 4; ++i) { o0[i] = acc[i][j] + bj; o1[i] = acc[4 + i][j] + bj; }
#pragma unroll
        for (int i = 0; i < 4; ++i) {
            qp[i]     += o0[i] * wqj;  kp[i]     += o0[i] * wkj;
            qp[4 + i] += o1[i] * wqj;  kp[4 + i] += o1[i] * wkj;
        }
        float* dst = sfT + ((size_t)b * D_ + d) * N_ + n0 + tx * 8;
        *(f32x4*)dst = o0;
        *(f32x4*)(dst + 4) = o1;
    }
#pragma unroll
    for (int i = 0; i < 8; ++i) {
        atomicAdd(&qs[tx * 8 + i], qp[i]);
        atomicAdd(&ks[tx * 8 + i], kp[i]);
    }
    __syncthreads();
    if (tid < 128) {
        qa[b * N_ + n0 + tid] = qs[tid];
        ka[b * N_ + n0 + tid] = ks[tid];
    }
}

// ---------------- K2: add biases, compute exp tables -------------------------
__global__ __launch_bounds__(256) void k_exp(const float* __restrict__ bq,
                                             const float* __restrict__ bk,
                                             float* __restrict__ qa, float* __restrict__ ka,
                                             float* __restrict__ Eq, float* __restrict__ eqs,
                                             float* __restrict__ Ek, float* __restrict__ eks) {
    int t = blockIdx.x * 256 + threadIdx.x;   // over B*N
    float aq = qa[t] + bq[0];
    float ak = ka[t] + bk[0];
    qa[t] = aq;            ka[t] = ak;
    Eq[t] = expf(aq);      eqs[t] = expf(0.01f * aq);
    Ek[t] = expf(ak);      eks[t] = expf(0.01f * ak);
}

// ---------------- K3: denom[b][j] = sum_i V(b,i,j) ---------------------------
__global__ __launch_bounds__(256) void k_denom(const unsigned int* __restrict__ bits,
                                               const float* __restrict__ qa,
                                               const float* __restrict__ ka,
                                               const float* __restrict__ Eq,
                                               const float* __restrict__ eqs,
                                               const float* __restrict__ Ek,
                                               const float* __restrict__ eks,
                                               float* __restrict__ denom) {
    int jt  = blockIdx.x;     // 0..7
    int b   = blockIdx.y;     // 0..15
    int seg = blockIdx.z;     // 0..7
    int j = jt * 256 + threadIdx.x;
    float qj  = qa[b * N_ + j];
    float Eqj = Eq[b * N_ + j];
    float eqj = eqs[b * N_ + j];
    int shift = j & 31;
    int wid   = j >> 5;
    float acc = 0.f;
    int i0 = seg * 256;
#pragma unroll 8
    for (int i = i0; i < i0 + 256; ++i) {
        float kk  = ka[b * N_ + i];
        float Ekk = Ek[b * N_ + i];
        float ekk = eks[b * N_ + i];
        unsigned int w = bits[i * 64 + wid];
        float z  = kk + qj;
        float f1 = z > 0.f ? Ekk : ekk;
        float f2 = z > 0.f ? Eqj : eqj;
        float v  = f1 * f2;
        acc += ((w >> shift) & 1u) ? v : 1.0f;
    }
    atomicAdd(&denom[b * N_ + j], acc);
}

// ---------------- K3b: Pt[b][d][j] = bf16(seq_ftsT / denom[b][j]) ------------
__global__ __launch_bounds__(256) void k_scale(const float* __restrict__ sfT,
                                               const float* __restrict__ denom,
                                               bf16_t* __restrict__ Pt) {
    size_t t = (size_t)blockIdx.x * 256 + threadIdx.x;
    int j  = (int)(t & (N_ - 1));
    int bd = (int)(t >> 11);
    int b  = bd >> 7;
    float v = sfT[t] / denom[b * N_ + j];
    Pt[t] = (bf16_t)v;
}

// ---------------- K4: vals = A @ P, LDS-staged B + in-register A -------------
// Block: 128 i x 128 d, 4 waves each owning 32 i. B-tile 128d x 64j bf16 in
// LDS (XOR-swizzled), double-buffered via global_load_lds width=16.
__global__ __launch_bounds__(256, 1) void k_attn(const float* __restrict__ qa,
                                                 const float* __restrict__ ka,
                                                 const float* __restrict__ Eq,
                                                 const float* __restrict__ eqs,
                                                 const float* __restrict__ Ek,
                                                 const float* __restrict__ eks,
                                                 const unsigned int* __restrict__ bits,
                                                 const bf16_t* __restrict__ Pt,
                                                 float* __restrict__ out) {
    __shared__ __align__(16) bf16_t lds[2][128 * 64];   // 32 KB
    int b     = blockIdx.y;
    int ibase = blockIdx.x * 128;
    int tid   = threadIdx.x;
    int w     = tid >> 6;
    int lane  = tid & 63;
    int m16   = lane & 15;
    int quad  = lane >> 4;
    int i0    = ibase + w * 32;

    int iA = i0 + m16, iB = i0 + 16 + m16;
    float kR0  = ka[b * N_ + iA],  kR1  = ka[b * N_ + iB];
    float EkR0 = Ek[b * N_ + iA],  EkR1 = Ek[b * N_ + iB];
    float ekR0 = eks[b * N_ + iA], ekR1 = eks[b * N_ + iB];
    const unsigned int* br0 = bits + (size_t)iA * 64;
    const unsigned int* br1 = bits + (size_t)iB * 64;
    const float* qp  = qa  + b * N_;
    const float* Eqp = Eq  + b * N_;
    const float* eqp = eqs + b * N_;
    const bf16_t* PtB = Pt + (size_t)b * D_ * N_;

    f32x4 acc[2][8];
#pragma unroll
    for (int c = 0; c < 2; ++c)
#pragma unroll
        for (int nt = 0; nt < 8; ++nt) acc[c][nt] = (f32x4){0.f, 0.f, 0.f, 0.f};

    // Stage 128d x 64j bf16 tile. LDS dest is lane-contiguous (required by
    // global_load_lds); the XOR swizzle is applied on the GLOBAL address:
    // LDS slot (d, c_phys) holds global j-chunk c_phys ^ (d&7).
    auto stage = [&](int bufi, int jb) {
#pragma unroll
        for (int t = 0; t < 4; ++t) {
            int off = (w * 4 + t) * 1024 + lane * 16;   // byte offset in tile
            int d   = off >> 7;                          // row (stride 128 B)
            int g   = ((off & 127) >> 4) ^ (d & 7);      // swizzled j-chunk
            const bf16_t* gp = PtB + (size_t)d * N_ + jb + g * 8;
            __builtin_amdgcn_global_load_lds(
                (const __attribute__((address_space(1))) void*)gp,
                (__attribute__((address_space(3))) void*)((char*)(&lds[bufi][0]) + (w * 4 + t) * 1024),
                16, 0, 0);
        }
    };

    stage(0, 0);
    __syncthreads();
    int buf = 0;
    for (int step = 0; step < N_ / 64; ++step) {
        int jb = step * 64;
        if (step + 1 < N_ / 64) stage(buf ^ 1, jb + 64);  // prefetch after barrier

        // ---- A fragments in registers (layout: m=lane&15, k=quad*8+t) ----
        bf16x8 af[2][2];   // [i-chunk][k-half]
#pragma unroll
        for (int h = 0; h < 2; ++h) {
            int j0 = jb + h * 32 + quad * 8;
            f32x4 q0 = *(const f32x4*)(qp + j0);
            f32x4 q1 = *(const f32x4*)(qp + j0 + 4);
            f32x4 E0 = *(const f32x4*)(Eqp + j0);
            f32x4 E1 = *(const f32x4*)(Eqp + j0 + 4);
            f32x4 e0 = *(const f32x4*)(eqp + j0);
            f32x4 e1 = *(const f32x4*)(eqp + j0 + 4);
            unsigned int w0 = br0[(jb >> 5) + h];
            unsigned int w1 = br1[(jb >> 5) + h];
#pragma unroll
            for (int t = 0; t < 8; ++t) {
                float qv = (t < 4) ? q0[t] : q1[t - 4];
                float Ev = (t < 4) ? E0[t] : E1[t - 4];
                float ev = (t < 4) ? e0[t] : e1[t - 4];
                int bit = quad * 8 + t;
                {
                    float z = kR0 + qv;
                    float v = ((z > 0.f) ? EkR0 : ekR0) * ((z > 0.f) ? Ev : ev);
                    af[0][h][t] = (bf16_t)(((w0 >> bit) & 1u) ? v : 1.0f);
                }
                {
                    float z = kR1 + qv;
                    float v = ((z > 0.f) ? EkR1 : ekR1) * ((z > 0.f) ? Ev : ev);
                    af[1][h][t] = (bf16_t)(((w1 >> bit) & 1u) ? v : 1.0f);
                }
            }
        }

        // ---- ds_read B-fragments + MFMA ----
#pragma unroll
        for (int h = 0; h < 2; ++h) {
            int cph = ((h * 4 + quad) ^ (m16 & 7)) * 8;   // element offset in row
#pragma unroll
            for (int nt = 0; nt < 8; ++nt) {
                int d = nt * 16 + m16;
                bf16x8 bf = *(const bf16x8*)&lds[buf][d * 64 + cph];
                acc[0][nt] = __builtin_amdgcn_mfma_f32_16x16x32_bf16(af[0][h], bf, acc[0][nt], 0, 0, 0);
                acc[1][nt] = __builtin_amdgcn_mfma_f32_16x16x32_bf16(af[1][h], bf, acc[1][nt], 0, 0, 0);
            }
        }
        __syncthreads();   // drains prefetch (in flight during compute) + guards buf reuse
        buf ^= 1;
    }

    // ---- epilogue: C layout col=lane&15 (d), row=quad*4+r (i) ----
#pragma unroll
    for (int c = 0; c < 2; ++c) {
        int irow = i0 + c * 16 + quad * 4;
#pragma unroll
        for (int nt = 0; nt < 8; ++nt) {
            int d = nt * 16 + m16;
#pragma unroll
            for (int r = 0; r < 4; ++r)
                out[((size_t)b * N_ + irow + r) * D_ + d] = acc[c][nt][r];
        }
    }
}

extern "C" void kernel_launch(void* const* d_in, const int* in_sizes, int n_in,
                              void* d_out, int out_size, void* d_ws, size_t ws_size,
                              hipStream_t stream) {
    const float* x   = (const float*)d_in[0];
    const float* adj = (const float*)d_in[1];
    const float* W   = (const float*)d_in[2];
    const float* be  = (const float*)d_in[3];
    const float* wq  = (const float*)d_in[4];
    const float* bq  = (const float*)d_in[5];
    const float* wk  = (const float*)d_in[6];
    const float* bk  = (const float*)d_in[7];
    float* out = (float*)d_out;

    char* ws = (char*)d_ws;
    size_t off = 0;
    float* sfT = (float*)(ws + off);  off += (size_t)B_ * D_ * N_ * 4;   // 16 MB
    bf16_t* Pt = (bf16_t*)(ws + off); off += (size_t)B_ * D_ * N_ * 2;   // 8 MB
    float* qa  = (float*)(ws + off);  off += (size_t)B_ * N_ * 4;
    float* ka  = (float*)(ws + off);  off += (size_t)B_ * N_ * 4;
    float* denom = (float*)(ws + off); off += (size_t)B_ * N_ * 4;
    float* Eq  = (float*)(ws + off);  off += (size_t)B_ * N_ * 4;
    float* eqs = (float*)(ws + off);  off += (size_t)B_ * N_ * 4;
    float* Ek  = (float*)(ws + off);  off += (size_t)B_ * N_ * 4;
    float* eks = (float*)(ws + off);  off += (size_t)B_ * N_ * 4;
    unsigned int* bits = (unsigned int*)(ws + off); off += (size_t)N_ * 64 * 4; // 512 KB

    hipMemsetAsync(denom, 0, (size_t)B_ * N_ * 4, stream);

    k_pack_adj<<<N_ * N_ / 256, 256, 0, stream>>>(adj, bits);
    k_emb<<<dim3(N_ / 128, B_), 256, 0, stream>>>(x, W, be, wq, wk, sfT, qa, ka);
    k_exp<<<B_ * N_ / 256, 256, 0, stream>>>(bq, bk, qa, ka, Eq, eqs, Ek, eks);
    k_denom<<<dim3(8, 16, 8), 256, 0, stream>>>(bits, qa, ka, Eq, eqs, Ek, eks, denom);
    k_scale<<<B_ * D_ * N_ / 256, 256, 0, stream>>>(sfT, denom, Pt);
    k_attn<<<dim3(N_ / 128, B_), 256, 0, stream>>>(qa, ka, Eq, eqs, Ek, eks, bits, Pt, out);
}

// Round 4
// 216.092 us; speedup vs baseline: 1.4858x; 1.0369x over previous
//
#include <hip/hip_runtime.h>
#include <hip/hip_bf16.h>
#include <stdint.h>

#define B_ 16
#define N_ 2048
#define D_ 128

typedef __bf16 bf16_t;
typedef bf16_t bf16x8 __attribute__((ext_vector_type(8)));
typedef float f32x4 __attribute__((ext_vector_type(4)));

// ---------------- K0: pack adj (fp32 0/1 matrix) into bitmask ----------------
__global__ __launch_bounds__(256) void k_pack_adj(const float* __restrict__ adj,
                                                  unsigned int* __restrict__ bits) {
    int t = blockIdx.x * 256 + threadIdx.x;       // over N*N
    float v = adj[t];
    unsigned long long m = __ballot(v > 0.5f);
    if ((t & 63) == 0) {
        int i = t >> 11;
        int j = t & 2047;
        bits[i * 64 + (j >> 5)]     = (unsigned int)m;
        bits[i * 64 + (j >> 5) + 1] = (unsigned int)(m >> 32);
    }
}

// ---------------- K1: emb GEMM (64n x 128d tile) + fused q/k + exps ----------
// seq_ftsT[b][d][n] = sum_k x[b][n][k]*W[d][k] + be[d]
// qa/ka/Eq/eqs/Ek/eks computed in-block (block owns n-range over all d).
__global__ __launch_bounds__(256, 2) void k_emb(const float* __restrict__ x,
                                                const float* __restrict__ W,
                                                const float* __restrict__ be,
                                                const float* __restrict__ wq,
                                                const float* __restrict__ bq,
                                                const float* __restrict__ wk,
                                                const float* __restrict__ bk,
                                                float* __restrict__ sfT,
                                                float* __restrict__ qa, float* __restrict__ ka,
                                                float* __restrict__ Eq, float* __restrict__ eqs,
                                                float* __restrict__ Ek, float* __restrict__ eks) {
    __shared__ float xs[32][68];     // [k][n]  64n + pad
    __shared__ float ws[32][132];    // [k][d]  128d + pad
    __shared__ float qs[64], ks[64];
    int b  = blockIdx.y;
    int n0 = blockIdx.x * 64;
    int tid = threadIdx.x;
    int tx = tid & 15, ty = tid >> 4;   // tx: n-dir (4 n), ty: d-dir (8 d)
    if (tid < 64) { qs[tid] = 0.f; ks[tid] = 0.f; }

    float acc[4][8] = {};               // [n][d]
    f32x4 xr[2], wr[4];

    auto loadregs = [&](int kc) {
#pragma unroll
        for (int s = 0; s < 2; ++s) {   // x tile: 64n x 32k = 512 f32x4
            int p = tid + 256 * s;
            int n = p >> 3, kq = p & 7;
            xr[s] = *(const f32x4*)(x + ((size_t)(b * N_ + n0 + n)) * D_ + kc * 32 + kq * 4);
        }
#pragma unroll
        for (int s = 0; s < 4; ++s) {   // W tile: 128d x 32k = 1024 f32x4
            int p = tid + 256 * s;
            int d = p >> 3, kq = p & 7;
            wr[s] = *(const f32x4*)(W + (size_t)d * D_ + kc * 32 + kq * 4);
        }
    };
    auto writelds = [&]() {
#pragma unroll
        for (int s = 0; s < 2; ++s) {
            int p = tid + 256 * s;
            int n = p >> 3, kq = p & 7;
#pragma unroll
            for (int u = 0; u < 4; ++u) xs[kq * 4 + u][n] = xr[s][u];
        }
#pragma unroll
        for (int s = 0; s < 4; ++s) {
            int p = tid + 256 * s;
            int d = p >> 3, kq = p & 7;
#pragma unroll
            for (int u = 0; u < 4; ++u) ws[kq * 4 + u][d] = wr[s][u];
        }
    };

    loadregs(0);
    for (int kc = 0; kc < 4; ++kc) {
        writelds();
        __syncthreads();
        if (kc < 3) loadregs(kc + 1);
#pragma unroll 4
        for (int k = 0; k < 32; ++k) {
            f32x4 xv  = *(const f32x4*)&xs[k][tx * 4];
            f32x4 wv0 = *(const f32x4*)&ws[k][ty * 8];
            f32x4 wv1 = *(const f32x4*)&ws[k][ty * 8 + 4];
#pragma unroll
            for (int i = 0; i < 4; ++i)
#pragma unroll
                for (int j = 0; j < 8; ++j)
                    acc[i][j] += xv[i] * ((j < 4) ? wv0[j] : wv1[j - 4]);
        }
        __syncthreads();
    }

    float qp[4] = {}, kp[4] = {};
#pragma unroll
    for (int j = 0; j < 8; ++j) {
        int d = ty * 8 + j;
        float bj  = be[d];
        float wqj = wq[d];
        float wkj = wk[d];
        f32x4 o;
#pragma unroll
        for (int i = 0; i < 4; ++i) {
            o[i] = acc[i][j] + bj;
            qp[i] += o[i] * wqj;
            kp[i] += o[i] * wkj;
        }
        *(f32x4*)(sfT + ((size_t)b * D_ + d) * N_ + n0 + tx * 4) = o;
    }
#pragma unroll
    for (int i = 0; i < 4; ++i) {
        atomicAdd(&qs[tx * 4 + i], qp[i]);
        atomicAdd(&ks[tx * 4 + i], kp[i]);
    }
    __syncthreads();
    if (tid < 64) {
        int idx = b * N_ + n0 + tid;
        float aq = qs[tid] + bq[0];
        float ak = ks[tid] + bk[0];
        qa[idx] = aq;          ka[idx] = ak;
        Eq[idx] = expf(aq);    eqs[idx] = expf(0.01f * aq);
        Ek[idx] = expf(ak);    eks[idx] = expf(0.01f * ak);
    }
}

// ---------------- K3: denom[b][j] = sum_i V(b,i,j) ---------------------------
__global__ __launch_bounds__(256) void k_denom(const unsigned int* __restrict__ bits,
                                               const float* __restrict__ qa,
                                               const float* __restrict__ ka,
                                               const float* __restrict__ Eq,
                                               const float* __restrict__ eqs,
                                               const float* __restrict__ Ek,
                                               const float* __restrict__ eks,
                                               float* __restrict__ denom) {
    int jt  = blockIdx.x;     // 0..7
    int b   = blockIdx.y;     // 0..15
    int seg = blockIdx.z;     // 0..7
    int j = jt * 256 + threadIdx.x;
    float qj  = qa[b * N_ + j];
    float Eqj = Eq[b * N_ + j];
    float eqj = eqs[b * N_ + j];
    int shift = j & 31;
    int wid   = j >> 5;
    float acc = 0.f;
    int i0 = seg * 256;
#pragma unroll 16
    for (int i = i0; i < i0 + 256; ++i) {
        float kk  = ka[b * N_ + i];
        float Ekk = Ek[b * N_ + i];
        float ekk = eks[b * N_ + i];
        unsigned int w = bits[i * 64 + wid];
        float z  = kk + qj;
        float f1 = z > 0.f ? Ekk : ekk;
        float f2 = z > 0.f ? Eqj : eqj;
        float v  = f1 * f2;
        acc += ((w >> shift) & 1u) ? v : 1.0f;
    }
    atomicAdd(&denom[b * N_ + j], acc);
}

// ---------------- K3b: Pt[b][d][j] = bf16(seq_ftsT / denom[b][j]) ------------
__global__ __launch_bounds__(256) void k_scale(const float* __restrict__ sfT,
                                               const float* __restrict__ denom,
                                               bf16_t* __restrict__ Pt) {
    size_t t4 = ((size_t)blockIdx.x * 256 + threadIdx.x) * 4;
    int j  = (int)(t4 & (N_ - 1));
    int b  = (int)(t4 >> 18);            // t4 >> 11 gives bd; bd >> 7 gives b
    f32x4 sv = *(const f32x4*)(sfT + t4);
    f32x4 dv = *(const f32x4*)(denom + b * N_ + j);
    bf16_t o[4];
#pragma unroll
    for (int u = 0; u < 4; ++u)
        o[u] = (bf16_t)(sv[u] * __builtin_amdgcn_rcpf(dv[u]));
    *(uint2*)(Pt + t4) = *(uint2*)o;
}

// ---------------- K4: vals = A @ P, LDS-staged B + in-register A -------------
// Block: 128 i x 128 d, 512 threads / 8 waves. Wave = 32 i x 64 d.
// B-tile 128d x 64j bf16 in LDS (XOR swizzle), dbuf via global_load_lds w=16.
__global__ __launch_bounds__(512, 2) void k_attn(const float* __restrict__ qa,
                                                 const float* __restrict__ ka,
                                                 const float* __restrict__ Eq,
                                                 const float* __restrict__ eqs,
                                                 const float* __restrict__ Ek,
                                                 const float* __restrict__ eks,
                                                 const unsigned int* __restrict__ bits,
                                                 const bf16_t* __restrict__ Pt,
                                                 float* __restrict__ out) {
    __shared__ __align__(16) bf16_t lds[2][128 * 64];   // 32 KB
    int b     = blockIdx.y;
    int ibase = blockIdx.x * 128;
    int tid   = threadIdx.x;
    int w     = tid >> 6;          // 0..7
    int lane  = tid & 63;
    int m16   = lane & 15;
    int quad  = lane >> 4;
    int ig    = w & 3;             // i-group (32 i)
    int d0    = (w >> 2) * 64;     // d-group (64 d)
    int i0    = ibase + ig * 32;

    int iA = i0 + m16, iB = i0 + 16 + m16;
    float kR0  = ka[b * N_ + iA],  kR1  = ka[b * N_ + iB];
    float EkR0 = Ek[b * N_ + iA],  EkR1 = Ek[b * N_ + iB];
    float ekR0 = eks[b * N_ + iA], ekR1 = eks[b * N_ + iB];
    const unsigned int* br0 = bits + (size_t)iA * 64;
    const unsigned int* br1 = bits + (size_t)iB * 64;
    const float* qp  = qa  + b * N_;
    const float* Eqp = Eq  + b * N_;
    const float* eqp = eqs + b * N_;
    const bf16_t* PtB = Pt + (size_t)b * D_ * N_;

    f32x4 acc[2][4];   // [i-chunk][d-tile]
#pragma unroll
    for (int c = 0; c < 2; ++c)
#pragma unroll
        for (int nt = 0; nt < 4; ++nt) acc[c][nt] = (f32x4){0.f, 0.f, 0.f, 0.f};

    // Stage 128d x 64j bf16 tile; 16 KB; 8 waves x 2 instrs x 1 KB.
    // XOR swizzle on the GLOBAL address (LDS dest must stay lane-contiguous).
    auto stage = [&](int bufi, int jb) {
#pragma unroll
        for (int t = 0; t < 2; ++t) {
            int off = (w * 2 + t) * 1024 + lane * 16;    // byte offset in tile
            int d   = off >> 7;                          // row (stride 128 B)
            int g   = ((off & 127) >> 4) ^ (d & 7);      // swizzled j-chunk
            const bf16_t* gp = PtB + (size_t)d * N_ + jb + g * 8;
            __builtin_amdgcn_global_load_lds(
                (const __attribute__((address_space(1))) void*)gp,
                (__attribute__((address_space(3))) void*)((char*)(&lds[bufi][0]) + (w * 2 + t) * 1024),
                16, 0, 0);
        }
    };

    stage(0, 0);
    __syncthreads();
    int buf = 0;
    for (int step = 0; step < N_ / 64; ++step) {
        int jb = step * 64;
        if (step + 1 < N_ / 64) stage(buf ^ 1, jb + 64);  // prefetch after barrier

        // ---- hoist ALL A-side inputs for this step ----
        f32x4 q0[2], q1[2], E0[2], E1[2], e0[2], e1[2];
#pragma unroll
        for (int h = 0; h < 2; ++h) {
            int j0 = jb + h * 32 + quad * 8;
            q0[h] = *(const f32x4*)(qp  + j0);
            q1[h] = *(const f32x4*)(qp  + j0 + 4);
            E0[h] = *(const f32x4*)(Eqp + j0);
            E1[h] = *(const f32x4*)(Eqp + j0 + 4);
            e0[h] = *(const f32x4*)(eqp + j0);
            e1[h] = *(const f32x4*)(eqp + j0 + 4);
        }
        uint2 wb0 = *(const uint2*)&br0[jb >> 5];
        uint2 wb1 = *(const uint2*)&br1[jb >> 5];

        // ---- A fragments (m=lane&15, k=quad*8+t) ----
        bf16x8 af[2][2];   // [i-chunk][j-half]
#pragma unroll
        for (int h = 0; h < 2; ++h) {
            unsigned int w0 = h ? wb0.y : wb0.x;
            unsigned int w1 = h ? wb1.y : wb1.x;
#pragma unroll
            for (int t = 0; t < 8; ++t) {
                float qv = (t < 4) ? q0[h][t] : q1[h][t - 4];
                float Ev = (t < 4) ? E0[h][t] : E1[h][t - 4];
                float ev = (t < 4) ? e0[h][t] : e1[h][t - 4];
                int bit = quad * 8 + t;
                {
                    float z = kR0 + qv;
                    float v = ((z > 0.f) ? EkR0 : ekR0) * ((z > 0.f) ? Ev : ev);
                    af[0][h][t] = (bf16_t)(((w0 >> bit) & 1u) ? v : 1.0f);
                }
                {
                    float z = kR1 + qv;
                    float v = ((z > 0.f) ? EkR1 : ekR1) * ((z > 0.f) ? Ev : ev);
                    af[1][h][t] = (bf16_t)(((w1 >> bit) & 1u) ? v : 1.0f);
                }
            }
        }

        // ---- ds_read B-fragments + MFMA ----
#pragma unroll
        for (int h = 0; h < 2; ++h) {
            int cph = ((h * 4 + quad) ^ (m16 & 7)) * 8;   // element offset in row
#pragma unroll
            for (int nt = 0; nt < 4; ++nt) {
                int d = d0 + nt * 16 + m16;
                bf16x8 bf = *(const bf16x8*)&lds[buf][d * 64 + cph];
                acc[0][nt] = __builtin_amdgcn_mfma_f32_16x16x32_bf16(af[0][h], bf, acc[0][nt], 0, 0, 0);
                acc[1][nt] = __builtin_amdgcn_mfma_f32_16x16x32_bf16(af[1][h], bf, acc[1][nt], 0, 0, 0);
            }
        }
        __syncthreads();   // drains prefetch + guards buf reuse
        buf ^= 1;
    }

    // ---- epilogue: C layout col=lane&15 (d), row=quad*4+r (i) ----
#pragma unroll
    for (int c = 0; c < 2; ++c) {
        int irow = i0 + c * 16 + quad * 4;
#pragma unroll
        for (int nt = 0; nt < 4; ++nt) {
            int d = d0 + nt * 16 + m16;
#pragma unroll
            for (int r = 0; r < 4; ++r)
                out[((size_t)b * N_ + irow + r) * D_ + d] = acc[c][nt][r];
        }
    }
}

extern "C" void kernel_launch(void* const* d_in, const int* in_sizes, int n_in,
                              void* d_out, int out_size, void* d_ws, size_t ws_size,
                              hipStream_t stream) {
    const float* x   = (const float*)d_in[0];
    const float* adj = (const float*)d_in[1];
    const float* W   = (const float*)d_in[2];
    const float* be  = (const float*)d_in[3];
    const float* wq  = (const float*)d_in[4];
    const float* bq  = (const float*)d_in[5];
    const float* wk  = (const float*)d_in[6];
    const float* bk  = (const float*)d_in[7];
    float* out = (float*)d_out;

    char* ws = (char*)d_ws;
    size_t off = 0;
    float* sfT = (float*)(ws + off);  off += (size_t)B_ * D_ * N_ * 4;   // 16 MB
    bf16_t* Pt = (bf16_t*)(ws + off); off += (size_t)B_ * D_ * N_ * 2;   // 8 MB
    float* qa  = (float*)(ws + off);  off += (size_t)B_ * N_ * 4;
    float* ka  = (float*)(ws + off);  off += (size_t)B_ * N_ * 4;
    float* denom = (float*)(ws + off); off += (size_t)B_ * N_ * 4;
    float* Eq  = (float*)(ws + off);  off += (size_t)B_ * N_ * 4;
    float* eqs = (float*)(ws + off);  off += (size_t)B_ * N_ * 4;
    float* Ek  = (float*)(ws + off);  off += (size_t)B_ * N_ * 4;
    float* eks = (float*)(ws + off);  off += (size_t)B_ * N_ * 4;
    unsigned int* bits = (unsigned int*)(ws + off); off += (size_t)N_ * 64 * 4; // 512 KB

    hipMemsetAsync(denom, 0, (size_t)B_ * N_ * 4, stream);

    k_pack_adj<<<N_ * N_ / 256, 256, 0, stream>>>(adj, bits);
    k_emb<<<dim3(N_ / 64, B_), 256, 0, stream>>>(x, W, be, wq, bq, wk, bk,
                                                 sfT, qa, ka, Eq, eqs, Ek, eks);
    k_denom<<<dim3(8, 16, 8), 256, 0, stream>>>(bits, qa, ka, Eq, eqs, Ek, eks, denom);
    k_scale<<<B_ * D_ * N_ / 1024, 256, 0, stream>>>(sfT, denom, Pt);
    k_attn<<<dim3(N_ / 128, B_), 512, 0, stream>>>(qa, ka, Eq, eqs, Ek, eks, bits, Pt, out);
}

// Round 5
// 204.292 us; speedup vs baseline: 1.5716x; 1.0578x over previous
//
#include <hip/hip_runtime.h>
#include <hip/hip_bf16.h>
#include <stdint.h>

#define B_ 16
#define N_ 2048
#define D_ 128

typedef __bf16 bf16_t;
typedef bf16_t bf16x8 __attribute__((ext_vector_type(8)));
typedef float f32x4 __attribute__((ext_vector_type(4)));

// ---------------- K0: pack adj (fp32 0/1 matrix) into bitmask ----------------
__global__ __launch_bounds__(256) void k_pack_adj(const float* __restrict__ adj,
                                                  unsigned int* __restrict__ bits) {
    int t = blockIdx.x * 256 + threadIdx.x;       // over N*N
    float v = adj[t];
    unsigned long long m = __ballot(v > 0.5f);
    if ((t & 63) == 0) {
        int i = t >> 11;
        int j = t & 2047;
        bits[i * 64 + (j >> 5)]     = (unsigned int)m;
        bits[i * 64 + (j >> 5) + 1] = (unsigned int)(m >> 32);
    }
}

// ---------------- K1: emb GEMM (64n x 128d tile) + fused q/k + exps ----------
__global__ __launch_bounds__(256, 2) void k_emb(const float* __restrict__ x,
                                                const float* __restrict__ W,
                                                const float* __restrict__ be,
                                                const float* __restrict__ wq,
                                                const float* __restrict__ bq,
                                                const float* __restrict__ wk,
                                                const float* __restrict__ bk,
                                                float* __restrict__ sfT,
                                                float* __restrict__ qa, float* __restrict__ ka,
                                                float* __restrict__ Eq, float* __restrict__ eqs,
                                                float* __restrict__ Ek, float* __restrict__ eks) {
    __shared__ float xs[32][68];     // [k][n]  64n + pad
    __shared__ float ws[32][132];    // [k][d]  128d + pad
    __shared__ float qs[64], ks[64];
    int b  = blockIdx.y;
    int n0 = blockIdx.x * 64;
    int tid = threadIdx.x;
    int tx = tid & 15, ty = tid >> 4;   // tx: n-dir (4 n), ty: d-dir (8 d)
    if (tid < 64) { qs[tid] = 0.f; ks[tid] = 0.f; }

    float acc[4][8] = {};               // [n][d]
    f32x4 xr[2], wr[4];

    auto loadregs = [&](int kc) {
#pragma unroll
        for (int s = 0; s < 2; ++s) {
            int p = tid + 256 * s;
            int n = p >> 3, kq = p & 7;
            xr[s] = *(const f32x4*)(x + ((size_t)(b * N_ + n0 + n)) * D_ + kc * 32 + kq * 4);
        }
#pragma unroll
        for (int s = 0; s < 4; ++s) {
            int p = tid + 256 * s;
            int d = p >> 3, kq = p & 7;
            wr[s] = *(const f32x4*)(W + (size_t)d * D_ + kc * 32 + kq * 4);
        }
    };
    auto writelds = [&]() {
#pragma unroll
        for (int s = 0; s < 2; ++s) {
            int p = tid + 256 * s;
            int n = p >> 3, kq = p & 7;
#pragma unroll
            for (int u = 0; u < 4; ++u) xs[kq * 4 + u][n] = xr[s][u];
        }
#pragma unroll
        for (int s = 0; s < 4; ++s) {
            int p = tid + 256 * s;
            int d = p >> 3, kq = p & 7;
#pragma unroll
            for (int u = 0; u < 4; ++u) ws[kq * 4 + u][d] = wr[s][u];
        }
    };

    loadregs(0);
    for (int kc = 0; kc < 4; ++kc) {
        writelds();
        __syncthreads();
        if (kc < 3) loadregs(kc + 1);
#pragma unroll 4
        for (int k = 0; k < 32; ++k) {
            f32x4 xv  = *(const f32x4*)&xs[k][tx * 4];
            f32x4 wv0 = *(const f32x4*)&ws[k][ty * 8];
            f32x4 wv1 = *(const f32x4*)&ws[k][ty * 8 + 4];
#pragma unroll
            for (int i = 0; i < 4; ++i)
#pragma unroll
                for (int j = 0; j < 8; ++j)
                    acc[i][j] += xv[i] * ((j < 4) ? wv0[j] : wv1[j - 4]);
        }
        __syncthreads();
    }

    float qp[4] = {}, kp[4] = {};
#pragma unroll
    for (int j = 0; j < 8; ++j) {
        int d = ty * 8 + j;
        float bj  = be[d];
        float wqj = wq[d];
        float wkj = wk[d];
        f32x4 o;
#pragma unroll
        for (int i = 0; i < 4; ++i) {
            o[i] = acc[i][j] + bj;
            qp[i] += o[i] * wqj;
            kp[i] += o[i] * wkj;
        }
        *(f32x4*)(sfT + ((size_t)b * D_ + d) * N_ + n0 + tx * 4) = o;
    }
#pragma unroll
    for (int i = 0; i < 4; ++i) {
        atomicAdd(&qs[tx * 4 + i], qp[i]);
        atomicAdd(&ks[tx * 4 + i], kp[i]);
    }
    __syncthreads();
    if (tid < 64) {
        int idx = b * N_ + n0 + tid;
        float aq = qs[tid] + bq[0];
        float ak = ks[tid] + bk[0];
        qa[idx] = aq;          ka[idx] = ak;
        Eq[idx] = expf(aq);    eqs[idx] = expf(0.01f * aq);
        Ek[idx] = expf(ak);    eks[idx] = expf(0.01f * ak);
    }
}

// ---------------- K3: denom[b][j] = sum_i V(b,i,j) ---------------------------
__global__ __launch_bounds__(256) void k_denom(const unsigned int* __restrict__ bits,
                                               const float* __restrict__ qa,
                                               const float* __restrict__ ka,
                                               const float* __restrict__ Eq,
                                               const float* __restrict__ eqs,
                                               const float* __restrict__ Ek,
                                               const float* __restrict__ eks,
                                               float* __restrict__ denom) {
    int jt  = blockIdx.x;     // 0..7
    int b   = blockIdx.y;     // 0..15
    int seg = blockIdx.z;     // 0..7
    int j = jt * 256 + threadIdx.x;
    float qj  = qa[b * N_ + j];
    float Eqj = Eq[b * N_ + j];
    float eqj = eqs[b * N_ + j];
    int shift = j & 31;
    int wid   = j >> 5;
    float acc = 0.f;
    int i0 = seg * 256;
#pragma unroll 16
    for (int i = i0; i < i0 + 256; ++i) {
        float kk  = ka[b * N_ + i];
        float Ekk = Ek[b * N_ + i];
        float ekk = eks[b * N_ + i];
        unsigned int w = bits[i * 64 + wid];
        float z  = kk + qj;
        float f1 = z > 0.f ? Ekk : ekk;
        float f2 = z > 0.f ? Eqj : eqj;
        float v  = f1 * f2;
        acc += ((w >> shift) & 1u) ? v : 1.0f;
    }
    atomicAdd(&denom[b * N_ + j], acc);
}

// ---------------- K3b: Pt[b][d][j] = bf16(seq_ftsT / denom[b][j]) ------------
__global__ __launch_bounds__(256) void k_scale(const float* __restrict__ sfT,
                                               const float* __restrict__ denom,
                                               bf16_t* __restrict__ Pt) {
    size_t t4 = ((size_t)blockIdx.x * 256 + threadIdx.x) * 4;
    int j  = (int)(t4 & (N_ - 1));
    int b  = (int)(t4 >> 18);
    f32x4 sv = *(const f32x4*)(sfT + t4);
    f32x4 dv = *(const f32x4*)(denom + b * N_ + j);
    bf16_t o[4];
#pragma unroll
    for (int u = 0; u < 4; ++u)
        o[u] = (bf16_t)(sv[u] * __builtin_amdgcn_rcpf(dv[u]));
    *(uint2*)(Pt + t4) = *(uint2*)o;
}

// ---------------- K4: vals = A @ P -------------------------------------------
// Block: 64 i x 128 d, 256 threads / 4 waves. Wave (ig,dg) = 32 i x 64 d.
// A-fragments generated ONCE per block (waves split j-halves, exchange via
// LDS A-buffer guarded by a raw lgkm-only barrier so the B-tile prefetch
// (global_load_lds, vmcnt) stays in flight across it).
__global__ __launch_bounds__(256, 2) void k_attn(const float* __restrict__ qa,
                                                 const float* __restrict__ ka,
                                                 const float* __restrict__ Eq,
                                                 const float* __restrict__ eqs,
                                                 const float* __restrict__ Ek,
                                                 const float* __restrict__ eks,
                                                 const unsigned int* __restrict__ bits,
                                                 const bf16_t* __restrict__ Pt,
                                                 float* __restrict__ out) {
    __shared__ __align__(16) bf16_t ldsB[2][128 * 64];   // 32 KB, B dbuf
    __shared__ __align__(16) bf16_t ldsA[4 * 2 * 64 * 8]; // 8 KB, A exchange
    int b     = blockIdx.y;
    int ibase = blockIdx.x * 64;
    int tid   = threadIdx.x;
    int w     = tid >> 6;          // 0..3
    int lane  = tid & 63;
    int m16   = lane & 15;
    int quad  = lane >> 4;
    int ig    = w & 1;             // i-group (32 i)
    int dg    = w >> 1;            // d-group (64 d)
    int h     = dg;                // j-half this wave generates A for

    // per-i constants for my 2 chunks (c = 2*ig, 2*ig+1), hoisted
    int iA = ibase + (2 * ig) * 16 + m16;
    int iB = iA + 16;
    float kR0  = ka[b * N_ + iA],  kR1  = ka[b * N_ + iB];
    float EkR0 = Ek[b * N_ + iA],  EkR1 = Ek[b * N_ + iB];
    float ekR0 = eks[b * N_ + iA], ekR1 = eks[b * N_ + iB];
    const unsigned int* brA = bits + (size_t)iA * 64;
    const unsigned int* brB = bits + (size_t)iB * 64;
    const float* qp  = qa  + b * N_;
    const float* Eqp = Eq  + b * N_;
    const float* eqp = eqs + b * N_;
    const bf16_t* PtB = Pt + (size_t)b * D_ * N_;

    f32x4 acc[2][4];   // [i-chunk][d-tile]
#pragma unroll
    for (int c = 0; c < 2; ++c)
#pragma unroll
        for (int nt = 0; nt < 4; ++nt) acc[c][nt] = (f32x4){0.f, 0.f, 0.f, 0.f};

    // Stage 128d x 64j bf16 tile (16 KB), XOR swizzle on the GLOBAL address.
    auto stage = [&](int bufi, int jb) {
#pragma unroll
        for (int t = 0; t < 4; ++t) {
            int off = t * 4096 + tid * 16;               // byte offset in tile
            int d   = off >> 7;                          // row (128 B = 64 j)
            int g   = ((off & 127) >> 4) ^ (d & 7);      // swizzled j-chunk
            const bf16_t* gp = PtB + (size_t)d * N_ + jb + g * 8;
            __builtin_amdgcn_global_load_lds(
                (const __attribute__((address_space(1))) void*)gp,
                (__attribute__((address_space(3))) void*)((char*)(&ldsB[bufi][0]) + off),
                16, 0, 0);
        }
    };

    stage(0, 0);
    __syncthreads();                 // drain initial stage
    int buf = 0;
    for (int step = 0; step < N_ / 64; ++step) {
        int jb = step * 64;

        // ---- A-side loads FIRST (so waiting on them leaves prefetch in flight)
        int j0 = jb + h * 32 + quad * 8;
        f32x4 q0 = *(const f32x4*)(qp  + j0);
        f32x4 q1 = *(const f32x4*)(qp  + j0 + 4);
        f32x4 E0 = *(const f32x4*)(Eqp + j0);
        f32x4 E1 = *(const f32x4*)(Eqp + j0 + 4);
        f32x4 e0 = *(const f32x4*)(eqp + j0);
        f32x4 e1 = *(const f32x4*)(eqp + j0 + 4);
        unsigned int wA = brA[(jb >> 5) + h];
        unsigned int wB = brB[(jb >> 5) + h];
        __builtin_amdgcn_sched_barrier(0);

        // ---- B prefetch for next step
        if (step + 1 < N_ / 64) stage(buf ^ 1, jb + 64);

        // ---- generate my half of the A-fragments (chunks 2ig, 2ig+1)
        bf16x8 afA, afB;
#pragma unroll
        for (int t = 0; t < 8; ++t) {
            float qv = (t < 4) ? q0[t] : q1[t - 4];
            float Ev = (t < 4) ? E0[t] : E1[t - 4];
            float ev = (t < 4) ? e0[t] : e1[t - 4];
            int bit = quad * 8 + t;
            {
                float z = kR0 + qv;
                float v = ((z > 0.f) ? EkR0 : ekR0) * ((z > 0.f) ? Ev : ev);
                afA[t] = (bf16_t)(((wA >> bit) & 1u) ? v : 1.0f);
            }
            {
                float z = kR1 + qv;
                float v = ((z > 0.f) ? EkR1 : ekR1) * ((z > 0.f) ? Ev : ev);
                afB[t] = (bf16_t)(((wB >> bit) & 1u) ? v : 1.0f);
            }
        }
        *(bf16x8*)((char*)ldsA + ((((2 * ig + 0) * 2 + h) * 64 + lane) * 16)) = afA;
        *(bf16x8*)((char*)ldsA + ((((2 * ig + 1) * 2 + h) * 64 + lane) * 16)) = afB;

        // raw barrier: drain LDS writes only — B prefetch (vmcnt) stays in flight
        asm volatile("s_waitcnt lgkmcnt(0)\n\ts_barrier" ::: "memory");

        // ---- read A-frags (both halves) + B-frags, MFMA
#pragma unroll
        for (int hh = 0; hh < 2; ++hh) {
            bf16x8 a0 = *(const bf16x8*)((char*)ldsA + ((((2 * ig + 0) * 2 + hh) * 64 + lane) * 16));
            bf16x8 a1 = *(const bf16x8*)((char*)ldsA + ((((2 * ig + 1) * 2 + hh) * 64 + lane) * 16));
            int cph = ((hh * 4 + quad) ^ (m16 & 7)) * 8;
#pragma unroll
            for (int nt = 0; nt < 4; ++nt) {
                int d = dg * 64 + nt * 16 + m16;
                bf16x8 bf = *(const bf16x8*)&ldsB[buf][d * 64 + cph];
                acc[0][nt] = __builtin_amdgcn_mfma_f32_16x16x32_bf16(a0, bf, acc[0][nt], 0, 0, 0);
                acc[1][nt] = __builtin_amdgcn_mfma_f32_16x16x32_bf16(a1, bf, acc[1][nt], 0, 0, 0);
            }
        }
        __syncthreads();   // drains prefetch + guards ldsA/ldsB reuse
        buf ^= 1;
    }

    // ---- epilogue: C layout col=lane&15 (d), row=quad*4+r (i) ----
#pragma unroll
    for (int c = 0; c < 2; ++c) {
        int irow = ibase + (2 * ig + c) * 16 + quad * 4;
#pragma unroll
        for (int nt = 0; nt < 4; ++nt) {
            int d = dg * 64 + nt * 16 + m16;
#pragma unroll
            for (int r = 0; r < 4; ++r)
                out[((size_t)b * N_ + irow + r) * D_ + d] = acc[c][nt][r];
        }
    }
}

extern "C" void kernel_launch(void* const* d_in, const int* in_sizes, int n_in,
                              void* d_out, int out_size, void* d_ws, size_t ws_size,
                              hipStream_t stream) {
    const float* x   = (const float*)d_in[0];
    const float* adj = (const float*)d_in[1];
    const float* W   = (const float*)d_in[2];
    const float* be  = (const float*)d_in[3];
    const float* wq  = (const float*)d_in[4];
    const float* bq  = (const float*)d_in[5];
    const float* wk  = (const float*)d_in[6];
    const float* bk  = (const float*)d_in[7];
    float* out = (float*)d_out;

    char* ws = (char*)d_ws;
    size_t off = 0;
    float* sfT = (float*)(ws + off);  off += (size_t)B_ * D_ * N_ * 4;   // 16 MB
    bf16_t* Pt = (bf16_t*)(ws + off); off += (size_t)B_ * D_ * N_ * 2;   // 8 MB
    float* qa  = (float*)(ws + off);  off += (size_t)B_ * N_ * 4;
    float* ka  = (float*)(ws + off);  off += (size_t)B_ * N_ * 4;
    float* denom = (float*)(ws + off); off += (size_t)B_ * N_ * 4;
    float* Eq  = (float*)(ws + off);  off += (size_t)B_ * N_ * 4;
    float* eqs = (float*)(ws + off);  off += (size_t)B_ * N_ * 4;
    float* Ek  = (float*)(ws + off);  off += (size_t)B_ * N_ * 4;
    float* eks = (float*)(ws + off);  off += (size_t)B_ * N_ * 4;
    unsigned int* bits = (unsigned int*)(ws + off); off += (size_t)N_ * 64 * 4; // 512 KB

    hipMemsetAsync(denom, 0, (size_t)B_ * N_ * 4, stream);

    k_pack_adj<<<N_ * N_ / 256, 256, 0, stream>>>(adj, bits);
    k_emb<<<dim3(N_ / 64, B_), 256, 0, stream>>>(x, W, be, wq, bq, wk, bk,
                                                 sfT, qa, ka, Eq, eqs, Ek, eks);
    k_denom<<<dim3(8, 16, 8), 256, 0, stream>>>(bits, qa, ka, Eq, eqs, Ek, eks, denom);
    k_scale<<<B_ * D_ * N_ / 1024, 256, 0, stream>>>(sfT, denom, Pt);
    k_attn<<<dim3(N_ / 64, B_), 256, 0, stream>>>(qa, ka, Eq, eqs, Ek, eks, bits, Pt, out);
}